// Round 7
// baseline (391.677 us; speedup 1.0000x reference)
//
#include <hip/hip_runtime.h>

#if __has_builtin(__builtin_amdgcn_exp2f)
#define EXP2F(x) __builtin_amdgcn_exp2f(x)
#else
#define EXP2F(x) exp2f(x)
#endif

typedef float v2f __attribute__((ext_vector_type(2)));

constexpr int B = 8, H = 512, W = 512;
constexpr int PLANE = H * W;              // 262144
constexpr int BSTRIDE = 2 * PLANE;
constexpr int NPIX = B * PLANE;           // 2097152
constexpr int PPITCH = 520;               // padded row pitch (4 left, 4 right)
constexpr int PXOFF  = 4;
constexpr int PPLANE = H * PPITCH;        // 266240
constexpr int PBUF   = 16 * PPLANE;       // 4,259,840 floats per padded tensor
constexpr float LOG2E = 1.4426950408889634f;

__device__ __forceinline__ float reluf(float v) { return v > 0.f ? v : 0.f; }
__device__ __forceinline__ float frcp(float v) { return __builtin_amdgcn_rcpf(v); }
__device__ __forceinline__ v2f vfma(v2f a, v2f b, v2f c) { return __builtin_elementwise_fma(a, b, c); }
__device__ __forceinline__ v2f vmax2(v2f a, v2f b) { return __builtin_elementwise_max(a, b); }
__device__ __forceinline__ v2f bc(float x) { v2f r; r.x = x; r.y = x; return r; }

struct AttnW {
    v2f wq0, wq1, bq;
    v2f wk0, wk1;
    v2f biasK[3];              // ((bk0+rh[r])*L, bk1*L)
    float rwL[3];              // rw[d]*L (ch1 additive)
    v2f wv0, wv1, bv;
};

__device__ __forceinline__ AttnW load_w(
    const float* wq, const float* bq, const float* wk, const float* bk,
    const float* wv, const float* bv, const float* rh, const float* rw, int i)
{
    AttnW P;
    P.wq0.x = wq[4*i];   P.wq0.y = wq[4*i+2];
    P.wq1.x = wq[4*i+1]; P.wq1.y = wq[4*i+3];
    P.bq.x  = bq[2*i];   P.bq.y  = bq[2*i+1];
    P.wk0.x = wk[4*i]   * LOG2E; P.wk0.y = wk[4*i+2] * LOG2E;
    P.wk1.x = wk[4*i+1] * LOG2E; P.wk1.y = wk[4*i+3] * LOG2E;
    float bk1L = bk[2*i+1] * LOG2E;
#pragma unroll
    for (int r = 0; r < 3; ++r) {
        P.biasK[r].x = (bk[2*i] + rh[3*i+r]) * LOG2E;
        P.biasK[r].y = bk1L;
    }
#pragma unroll
    for (int d = 0; d < 3; ++d) P.rwL[d] = rw[3*i+d] * LOG2E;
    P.wv0.x = wv[4*i];   P.wv0.y = wv[4*i+2];
    P.wv1.x = wv[4*i+1]; P.wv1.y = wv[4*i+3];
    P.bv.x  = bv[2*i];   P.bv.y  = bv[2*i+1];
    return P;
}

__device__ __forceinline__ void attn_strip(
    const v2f (&t)[3][6], const AttnW& P, v2f (&o)[4])
{
    v2f kk[3][6], vv[3][6];
#pragma unroll
    for (int r = 0; r < 3; ++r)
#pragma unroll
        for (int c = 0; c < 6; ++c) {
            v2f u0 = bc(t[r][c].x), u1 = bc(t[r][c].y);
            kk[r][c] = vfma(P.wk0, u0, vfma(P.wk1, u1, P.biasK[r]));
            vv[r][c] = vfma(P.wv0, u0, vfma(P.wv1, u1, P.bv));
        }
#pragma unroll
    for (int px = 0; px < 4; ++px) {
        v2f q = vfma(P.wq0, bc(t[1][px+1].x), vfma(P.wq1, bc(t[1][px+1].y), P.bq));
        v2f addv[3];
#pragma unroll
        for (int d = 0; d < 3; ++d) { addv[d].x = 0.f; addv[d].y = q.y * P.rwL[d]; }
        v2f s[9];
#pragma unroll
        for (int r = 0; r < 3; ++r)
#pragma unroll
            for (int d = 0; d < 3; ++d)
                s[r*3+d] = vfma(q, kk[r][px+d], addv[d]);
        v2f m = vmax2(vmax2(vmax2(vmax2(s[0], s[1]), vmax2(s[2], s[3])),
                            vmax2(vmax2(s[4], s[5]), vmax2(s[6], s[7]))), s[8]);
        v2f sum = bc(0.f), acc = bc(0.f);
#pragma unroll
        for (int r = 0; r < 3; ++r)
#pragma unroll
            for (int d = 0; d < 3; ++d) {
                v2f dd = s[r*3+d] - m;
                v2f e; e.x = EXP2F(dd.x); e.y = EXP2F(dd.y);
                sum += e;
                acc = vfma(e, vv[r][px+d], acc);
            }
        v2f rs; rs.x = frcp(sum.x); rs.y = frcp(sum.y);
        o[px] = acc * rs;
    }
}

__device__ __forceinline__ void write_pads(float* outp, int b2, int y, int x0)
{
    float4 z = make_float4(0.f, 0.f, 0.f, 0.f);
    if (x0 == 0) {
        int pb = b2 * PPLANE + y * PPITCH;
        *reinterpret_cast<float4*>(outp + pb)          = z;
        *reinterpret_cast<float4*>(outp + pb + PPLANE) = z;
    } else if (x0 == W - 4) {
        int pb = b2 * PPLANE + y * PPITCH + PXOFF + W;
        *reinterpret_cast<float4*>(outp + pb)          = z;
        *reinterpret_cast<float4*>(outp + pb + PPLANE) = z;
    }
}

// ---------------- stage bodies ----------------

__device__ __forceinline__ void attn_in_body(
    unsigned s, const float* __restrict__ x, float* outp, const AttnW& P)
{
    int x0 = (s & 127) * 4;
    int y  = (s >> 7) & 511;
    int b  = s >> 16;

    const float* xb = x + b * BSTRIDE;
    bool rowv[3] = { y > 0, true, y < H - 1 };
    int  yr[3]   = { y > 0 ? y - 1 : 0, y, y < H - 1 ? y + 1 : H - 1 };
    bool lv   = x0 > 0;
    bool rvld = x0 < W - 4;
    int  xl = lv ? x0 - 1 : 0;
    int  xr = rvld ? x0 + 4 : W - 1;

    v2f t[3][6];
#pragma unroll
    for (int r = 0; r < 3; ++r) {
        const float* p0 = xb + yr[r] * W;
        const float* p1 = p0 + PLANE;
        float4 a0 = *reinterpret_cast<const float4*>(p0 + x0);
        float4 a1 = *reinterpret_cast<const float4*>(p1 + x0);
        float u0[6] = { p0[xl], a0.x, a0.y, a0.z, a0.w, p0[xr] };
        float u1[6] = { p1[xl], a1.x, a1.y, a1.z, a1.w, p1[xr] };
        bool rv_ = rowv[r];
#pragma unroll
        for (int c = 0; c < 6; ++c) {
            bool ok = rv_ && (c > 0 || lv) && (c < 5 || rvld);
            t[r][c].x = ok ? reluf(u0[c]) : 0.f;
            t[r][c].y = ok ? reluf(u1[c]) : 0.f;
        }
    }

    v2f o[4];
    attn_strip(t, P, o);

    int ob = (b * 2) * PPLANE + y * PPITCH + x0 + PXOFF;
    *reinterpret_cast<float4*>(outp + ob)          = make_float4(o[0].x, o[1].x, o[2].x, o[3].x);
    *reinterpret_cast<float4*>(outp + ob + PPLANE) = make_float4(o[0].y, o[1].y, o[2].y, o[3].y);
    write_pads(outp, b * 2, y, x0);
}

template<int NRES, bool PADOUT>
__device__ __forceinline__ void attn_fast_body(
    unsigned s, const float* xp, float* outp,
    int oPlane, int oPitch, int oXoff,
    const float* res0, int aPlane, int aPitch, int aXoff,
    const float* res1, int cPlane, int cPitch, int cXoff,
    const AttnW& P)
{
    int x0 = (s & 127) * 4;
    int y  = (s >> 7) & 511;
    int b  = s >> 16;

    const float* xb0 = xp + (b * 2) * PPLANE + x0 + PXOFF;
    v2f t[3][6];
#pragma unroll
    for (int r = 0; r < 3; ++r) {
        int gy = y - 1 + r;
        bool ok = (unsigned)gy < (unsigned)H;
        int gyc = ok ? gy : y;
        const float* p0 = xb0 + gyc * PPITCH;
        const float* p1 = p0 + PPLANE;
        float4 a0 = *reinterpret_cast<const float4*>(p0);
        float4 a1 = *reinterpret_cast<const float4*>(p1);
        float e0l = p0[-1], e0r = p0[4];
        float e1l = p1[-1], e1r = p1[4];
        if (ok) {
            t[r][0].x=reluf(e0l);  t[r][0].y=reluf(e1l);
            t[r][1].x=reluf(a0.x); t[r][1].y=reluf(a1.x);
            t[r][2].x=reluf(a0.y); t[r][2].y=reluf(a1.y);
            t[r][3].x=reluf(a0.z); t[r][3].y=reluf(a1.z);
            t[r][4].x=reluf(a0.w); t[r][4].y=reluf(a1.w);
            t[r][5].x=reluf(e0r);  t[r][5].y=reluf(e1r);
        } else {
#pragma unroll
            for (int c = 0; c < 6; ++c) { t[r][c].x = 0.f; t[r][c].y = 0.f; }
        }
    }

    v2f o[4];
    attn_strip(t, P, o);

    if (NRES >= 1) {
        int rb = (b * 2) * aPlane + y * aPitch + x0 + aXoff;
        float4 ra = *reinterpret_cast<const float4*>(res0 + rb);
        float4 rbv = *reinterpret_cast<const float4*>(res0 + rb + aPlane);
        o[0].x+=ra.x; o[1].x+=ra.y; o[2].x+=ra.z; o[3].x+=ra.w;
        o[0].y+=rbv.x; o[1].y+=rbv.y; o[2].y+=rbv.z; o[3].y+=rbv.w;
    }
    if (NRES >= 2) {
        int rb = (b * 2) * cPlane + y * cPitch + x0 + cXoff;
        float4 ra = *reinterpret_cast<const float4*>(res1 + rb);
        float4 rbv = *reinterpret_cast<const float4*>(res1 + rb + cPlane);
        o[0].x+=ra.x; o[1].x+=ra.y; o[2].x+=ra.z; o[3].x+=ra.w;
        o[0].y+=rbv.x; o[1].y+=rbv.y; o[2].y+=rbv.z; o[3].y+=rbv.w;
    }

    int ob = (b * 2) * oPlane + y * oPitch + x0 + oXoff;
    *reinterpret_cast<float4*>(outp + ob)          = make_float4(o[0].x, o[1].x, o[2].x, o[3].x);
    *reinterpret_cast<float4*>(outp + ob + oPlane) = make_float4(o[0].y, o[1].y, o[2].y, o[3].y);
    if (PADOUT) write_pads(outp, b * 2, y, x0);
}

__device__ __forceinline__ void conv_body(
    unsigned s, const float* u, const float (&w)[18], float cb0, float* o)
{
    int x0 = (s & 127) * 4;
    int y  = (s >> 7) & 511;
    int b  = s >> 16;

    int yy[3];
#pragma unroll
    for (int i = 0; i < 3; ++i) {
        int t = y + i - 1;
        if (t < 0) t = -t;
        if (t > H - 1) t = 2 * (H - 1) - t;
        yy[i] = t;
    }
    int xl = x0 - 1; if (xl < 0) xl = 1;
    int xr = x0 + 4; if (xr > W - 1) xr = 2 * (W - 1) - xr;

    float acc[4] = { cb0, cb0, cb0, cb0 };
#pragma unroll
    for (int c = 0; c < 2; ++c) {
        const float* up = u + b * BSTRIDE + c * PLANE;
#pragma unroll
        for (int i = 0; i < 3; ++i) {
            const float* row = up + yy[i] * W;
            float4 a = *reinterpret_cast<const float4*>(row + x0);
            float t[6] = { row[xl], a.x, a.y, a.z, a.w, row[xr] };
#pragma unroll
            for (int j = 0; j < 3; ++j) {
                float wc = w[c * 9 + i * 3 + j];
#pragma unroll
                for (int px = 0; px < 4; ++px)
                    acc[px] = fmaf(t[px + j], wc, acc[px]);
            }
        }
    }
    float4 ov;
    ov.x = frcp(1.f + EXP2F(-acc[0] * LOG2E));
    ov.y = frcp(1.f + EXP2F(-acc[1] * LOG2E));
    ov.z = frcp(1.f + EXP2F(-acc[2] * LOG2E));
    ov.w = frcp(1.f + EXP2F(-acc[3] * LOG2E));
    *reinterpret_cast<float4*>(o + b * PLANE + y * W + x0) = ov;
}

__device__ __forceinline__ void up_body(unsigned p, const float* o, float* up)
{
    int b  = p >> 18;
    int y  = (p >> 8) & 1023;
    int x0 = (p & 255) * 4;

    const float scale = 511.0f / 1023.0f;
    float fy = y * scale;
    int y0 = (int)fy;
    float wy = fy - y0;
    int y1 = min(y0 + 1, H - 1);

    const float* ob = o + b * PLANE;
    const float* row0 = ob + y0 * W;
    const float* row1 = ob + y1 * W;

    float4 ov;
    float* ovp = &ov.x;
#pragma unroll
    for (int j = 0; j < 4; ++j) {
        float fx = (x0 + j) * scale;
        int xi = (int)fx;
        float wx = fx - xi;
        int xi1 = min(xi + 1, W - 1);
        float v00 = row0[xi], v01 = row0[xi1];
        float v10 = row1[xi], v11 = row1[xi1];
        float top = fmaf(v01 - v00, wx, v00);
        float bot = fmaf(v11 - v10, wx, v10);
        ovp[j] = fmaf(bot - top, wy, top);
    }
    *reinterpret_cast<float4*>(up + ((long)b << 20) + y * 1024 + x0) = ov;
}

// ---------------- grid barrier (device-scope, sense via generation counter) ----------------
__device__ __forceinline__ void grid_barrier(unsigned* bar, unsigned nblocks)
{
    __syncthreads();
    if (threadIdx.x == 0) {
        __threadfence();
        unsigned g = __hip_atomic_load(&bar[1], __ATOMIC_RELAXED, __HIP_MEMORY_SCOPE_AGENT);
        unsigned arrived = __hip_atomic_fetch_add(&bar[0], 1u, __ATOMIC_ACQ_REL, __HIP_MEMORY_SCOPE_AGENT);
        if (arrived == nblocks - 1) {
            __hip_atomic_store(&bar[0], 0u, __ATOMIC_RELAXED, __HIP_MEMORY_SCOPE_AGENT);
            __hip_atomic_fetch_add(&bar[1], 1u, __ATOMIC_ACQ_REL, __HIP_MEMORY_SCOPE_AGENT);
        } else {
            while (__hip_atomic_load(&bar[1], __ATOMIC_ACQUIRE, __HIP_MEMORY_SCOPE_AGENT) == g)
                __builtin_amdgcn_s_sleep(1);
        }
        __threadfence();
    }
    __syncthreads();
}

// balanced contiguous partition of `total` work-units over gridDim.x blocks
__device__ __forceinline__ void myrange(unsigned total, unsigned& w0, unsigned& w1)
{
    unsigned g = gridDim.x;
    w0 = (total * blockIdx.x) / g;
    w1 = (total * (blockIdx.x + 1)) / g;
}

// ---------------- megakernel: all 7 stages, 6 grid barriers ----------------
__global__ __launch_bounds__(256) void mega_kernel(
    const float* __restrict__ in1, const float* __restrict__ in2,
    float* A, float* Bb, float* C, float* out,
    const float* __restrict__ wq, const float* __restrict__ bq,
    const float* __restrict__ wk, const float* __restrict__ bk,
    const float* __restrict__ wv, const float* __restrict__ bv,
    const float* __restrict__ rh, const float* __restrict__ rw,
    const float* __restrict__ cw, const float* __restrict__ cb,
    unsigned* bar)
{
    const unsigned nb = gridDim.x;
    const unsigned tid = threadIdx.x;
    unsigned w0, w1;

    // stage 0: t1 = attn0(relu(in1)) -> A ; t3 = attn2(relu(in2)) -> B   (4096 units)
    myrange(4096, w0, w1);
    {
        unsigned mid = w1 < 2048 ? w1 : 2048;
        if (w0 < mid) {
            AttnW PA = load_w(wq, bq, wk, bk, wv, bv, rh, rw, 0);
            for (unsigned wb = w0; wb < mid; ++wb)
                attn_in_body((wb << 8) | tid, in1, A, PA);
        }
        unsigned lo = w0 > 2048 ? w0 : 2048;
        if (lo < w1) {
            AttnW PB = load_w(wq, bq, wk, bk, wv, bv, rh, rw, 2);
            for (unsigned wb = lo; wb < w1; ++wb)
                attn_in_body(((wb - 2048) << 8) | tid, in2, Bb, PB);
        }
    }
    grid_barrier(bar, nb);

    // stage 1: r1 = attn1(relu(t1)) + in1 -> C
    myrange(2048, w0, w1);
    {
        AttnW P = load_w(wq, bq, wk, bk, wv, bv, rh, rw, 1);
        for (unsigned wb = w0; wb < w1; ++wb)
            attn_fast_body<1,false>((wb << 8) | tid, A, C, PLANE, W, 0,
                in1, PLANE, W, 0, nullptr, 0, 0, 0, P);
    }
    grid_barrier(bar, nb);

    // stage 2: s = attn3(relu(t3)) + in2 + r1 -> A (padded)
    myrange(2048, w0, w1);
    {
        AttnW P = load_w(wq, bq, wk, bk, wv, bv, rh, rw, 3);
        for (unsigned wb = w0; wb < w1; ++wb)
            attn_fast_body<2,true>((wb << 8) | tid, Bb, A, PPLANE, PPITCH, PXOFF,
                in2, PLANE, W, 0, C, PLANE, W, 0, P);
    }
    grid_barrier(bar, nb);

    // stage 3: t5 = attn4(relu(s)) -> B (padded)
    myrange(2048, w0, w1);
    {
        AttnW P = load_w(wq, bq, wk, bk, wv, bv, rh, rw, 4);
        for (unsigned wb = w0; wb < w1; ++wb)
            attn_fast_body<0,true>((wb << 8) | tid, A, Bb, PPLANE, PPITCH, PXOFF,
                nullptr, 0, 0, 0, nullptr, 0, 0, 0, P);
    }
    grid_barrier(bar, nb);

    // stage 4: u = attn5(relu(t5)) + s -> C
    myrange(2048, w0, w1);
    {
        AttnW P = load_w(wq, bq, wk, bk, wv, bv, rh, rw, 5);
        for (unsigned wb = w0; wb < w1; ++wb)
            attn_fast_body<1,false>((wb << 8) | tid, Bb, C, PLANE, W, 0,
                A, PPLANE, PPITCH, PXOFF, nullptr, 0, 0, 0, P);
    }
    grid_barrier(bar, nb);

    // stage 5: o = sigmoid(conv3x3(reflect_pad(u))) -> out[0:2M]
    myrange(2048, w0, w1);
    {
        float w18[18];
#pragma unroll
        for (int i = 0; i < 18; ++i) w18[i] = cw[i];
        float cb0 = cb[0];
        for (unsigned wb = w0; wb < w1; ++wb)
            conv_body((wb << 8) | tid, C, w18, cb0, out);
    }
    grid_barrier(bar, nb);

    // stage 6: up = bilinear2x(o) -> out[2M:]
    myrange(8192, w0, w1);
    for (unsigned wb = w0; wb < w1; ++wb)
        up_body((wb << 8) | tid, out, out + NPIX);
}

// ---------------- fallback kernels (round-6 proven path) ----------------

__global__ __launch_bounds__(256) void attn_in_kernel(
    const float* __restrict__ xA, const float* __restrict__ xB,
    float* outA, float* outB,
    const float* __restrict__ wq, const float* __restrict__ bq,
    const float* __restrict__ wk, const float* __restrict__ bk,
    const float* __restrict__ wv, const float* __restrict__ bv,
    const float* __restrict__ rh, const float* __restrict__ rw,
    int piA, int piB)
{
    int bid = blockIdx.x;
    bool second = bid >= 2048;
    AttnW P = load_w(wq, bq, wk, bk, wv, bv, rh, rw, second ? piB : piA);
    unsigned s = (unsigned)(second ? bid - 2048 : bid) * 256u + threadIdx.x;
    attn_in_body(s, second ? xB : xA, second ? outB : outA, P);
}

template<int NRES, bool PADOUT>
__global__ __launch_bounds__(256) void attn_fast_kernel(
    const float* xp, float* outp, int oPlane, int oPitch, int oXoff,
    const float* res0, int aPlane, int aPitch, int aXoff,
    const float* res1, int cPlane, int cPitch, int cXoff,
    const float* __restrict__ wq, const float* __restrict__ bq,
    const float* __restrict__ wk, const float* __restrict__ bk,
    const float* __restrict__ wv, const float* __restrict__ bv,
    const float* __restrict__ rh, const float* __restrict__ rw, int pi)
{
    AttnW P = load_w(wq, bq, wk, bk, wv, bv, rh, rw, pi);
    unsigned s = blockIdx.x * 256u + threadIdx.x;
    attn_fast_body<NRES,PADOUT>(s, xp, outp, oPlane, oPitch, oXoff,
        res0, aPlane, aPitch, aXoff, res1, cPlane, cPitch, cXoff, P);
}

__global__ __launch_bounds__(256) void conv_sig4_kernel(
    const float* u, const float* __restrict__ cw, const float* __restrict__ cb,
    float* o)
{
    float w18[18];
#pragma unroll
    for (int i = 0; i < 18; ++i) w18[i] = cw[i];
    conv_body(blockIdx.x * 256u + threadIdx.x, u, w18, cb[0], o);
}

__global__ __launch_bounds__(256) void upsample4_kernel(const float* o, float* up)
{
    up_body(blockIdx.x * 256u + threadIdx.x, o, up);
}

extern "C" void kernel_launch(void* const* d_in, const int* in_sizes, int n_in,
                              void* d_out, int out_size, void* d_ws, size_t ws_size,
                              hipStream_t stream) {
    const float* in1 = (const float*)d_in[0];
    const float* in2 = (const float*)d_in[1];
    const float* wq  = (const float*)d_in[2];
    const float* bq  = (const float*)d_in[3];
    const float* wk  = (const float*)d_in[4];
    const float* bk  = (const float*)d_in[5];
    const float* wv  = (const float*)d_in[6];
    const float* bv  = (const float*)d_in[7];
    const float* rh  = (const float*)d_in[8];
    const float* rw  = (const float*)d_in[9];
    const float* cw  = (const float*)d_in[10];
    const float* cb  = (const float*)d_in[11];

    float* out = (float*)d_out;
    float* A  = out;              // padded tensor 0
    float* Bb = out + PBUF;       // padded tensor 1 (ends at 8,519,680)
    float* C  = (float*)d_ws;     // unpadded scratch (16 MB)
    // barrier state in the d_out spare region (only written by upsample stage,
    // after the last barrier). memset each launch -> deterministic replays.
    unsigned* bar = (unsigned*)(out + (2 * PBUF) + 64);
    (void)ws_size; (void)out_size; (void)n_in; (void)in_sizes;

    // ---- try cooperative megakernel ----
    int nbq = 0;
    hipError_t qe = hipOccupancyMaxActiveBlocksPerMultiprocessor(
        &nbq, reinterpret_cast<const void*>(mega_kernel), 256, 0);
    if (qe == hipSuccess && nbq > 0) {
        unsigned grid = (unsigned)nbq * 256u;   // 256 CUs on MI355X
        if (grid > 2048u) grid = 2048u;
        hipMemsetAsync(bar, 0, 2 * sizeof(unsigned), stream);
        const float *a_in1 = in1, *a_in2 = in2;
        float *a_A = A, *a_B = Bb, *a_C = C, *a_out = out;
        const float *a_wq = wq, *a_bq = bq, *a_wk = wk, *a_bk = bk;
        const float *a_wv = wv, *a_bv = bv, *a_rh = rh, *a_rw = rw;
        const float *a_cw = cw, *a_cb = cb;
        unsigned* a_bar = bar;
        void* args[] = {
            (void*)&a_in1, (void*)&a_in2, (void*)&a_A, (void*)&a_B,
            (void*)&a_C, (void*)&a_out,
            (void*)&a_wq, (void*)&a_bq, (void*)&a_wk, (void*)&a_bk,
            (void*)&a_wv, (void*)&a_bv, (void*)&a_rh, (void*)&a_rw,
            (void*)&a_cw, (void*)&a_cb, (void*)&a_bar };
        hipError_t le = hipLaunchCooperativeKernel(
            reinterpret_cast<const void*>(mega_kernel),
            dim3(grid), dim3(256), args, 0, stream);
        if (le == hipSuccess) return;
    }

    // ---- fallback: proven round-6 multi-kernel path ----
    dim3 blk(256);
    attn_in_kernel<<<4096, blk, 0, stream>>>(in1, in2, A, Bb,
        wq, bq, wk, bk, wv, bv, rh, rw, 0, 2);
    attn_fast_kernel<1,false><<<2048, blk, 0, stream>>>(A, C, PLANE, W, 0,
        in1, PLANE, W, 0, nullptr, 0, 0, 0,
        wq, bq, wk, bk, wv, bv, rh, rw, 1);
    attn_fast_kernel<2,true><<<2048, blk, 0, stream>>>(Bb, A, PPLANE, PPITCH, PXOFF,
        in2, PLANE, W, 0, C, PLANE, W, 0,
        wq, bq, wk, bk, wv, bv, rh, rw, 3);
    attn_fast_kernel<0,true><<<2048, blk, 0, stream>>>(A, Bb, PPLANE, PPITCH, PXOFF,
        nullptr, 0, 0, 0, nullptr, 0, 0, 0,
        wq, bq, wk, bk, wv, bv, rh, rw, 4);
    attn_fast_kernel<1,false><<<2048, blk, 0, stream>>>(Bb, C, PLANE, W, 0,
        A, PPLANE, PPITCH, PXOFF, nullptr, 0, 0, 0,
        wq, bq, wk, bk, wv, bv, rh, rw, 5);
    conv_sig4_kernel<<<2048, blk, 0, stream>>>(C, cw, cb, out);
    upsample4_kernel<<<8192, blk, 0, stream>>>(out, out + NPIX);
}

// Round 8
// 113.738 us; speedup vs baseline: 3.4437x; 3.4437x over previous
//
#include <hip/hip_runtime.h>

#if __has_builtin(__builtin_amdgcn_exp2f)
#define EXP2F(x) __builtin_amdgcn_exp2f(x)
#else
#define EXP2F(x) exp2f(x)
#endif

typedef float v2f __attribute__((ext_vector_type(2)));

constexpr int B = 8, H = 512, W = 512;
constexpr int PLANE = H * W;              // 262144
constexpr int BSTRIDE = 2 * PLANE;
constexpr int NPIX = B * PLANE;           // 2097152
constexpr int PPITCH = 520;               // padded row pitch (4 left, 4 right)
constexpr int PXOFF  = 4;
constexpr int PPLANE = H * PPITCH;        // 266240
constexpr int PBUF   = 16 * PPLANE;       // 4,259,840 floats per padded tensor
constexpr float LOG2E = 1.4426950408889634f;

__device__ __forceinline__ float reluf(float v) { return v > 0.f ? v : 0.f; }
__device__ __forceinline__ float frcp(float v) { return __builtin_amdgcn_rcpf(v); }
__device__ __forceinline__ v2f vfma(v2f a, v2f b, v2f c) { return __builtin_elementwise_fma(a, b, c); }
__device__ __forceinline__ v2f vmax2(v2f a, v2f b) { return __builtin_elementwise_max(a, b); }
__device__ __forceinline__ v2f bc(float x) { v2f r; r.x = x; r.y = x; return r; }

// XCD-aware bijective work swizzle (8 XCDs, nwg % 8 == 0):
// hardware round-robins consecutive blockIdx across XCDs; remap so each XCD
// gets a CONTIGUOUS band of work ids (rows / batches) -> halo + producer->
// consumer reuse stays in the XCD-private 4MB L2.
__device__ __forceinline__ unsigned swz8(unsigned bid, unsigned nwg)
{
    return (bid & 7u) * (nwg >> 3) + (bid >> 3);
}

struct AttnW {
    v2f wq0, wq1, bq;
    v2f wk0, wk1;
    v2f biasK[3];              // ((bk0+rh[r])*L, bk1*L)
    float rwL[3];              // rw[d]*L (ch1 additive)
    v2f wv0, wv1, bv;
};

__device__ __forceinline__ AttnW load_w(
    const float* wq, const float* bq, const float* wk, const float* bk,
    const float* wv, const float* bv, const float* rh, const float* rw, int i)
{
    AttnW P;
    P.wq0.x = wq[4*i];   P.wq0.y = wq[4*i+2];
    P.wq1.x = wq[4*i+1]; P.wq1.y = wq[4*i+3];
    P.bq.x  = bq[2*i];   P.bq.y  = bq[2*i+1];
    P.wk0.x = wk[4*i]   * LOG2E; P.wk0.y = wk[4*i+2] * LOG2E;
    P.wk1.x = wk[4*i+1] * LOG2E; P.wk1.y = wk[4*i+3] * LOG2E;
    float bk1L = bk[2*i+1] * LOG2E;
#pragma unroll
    for (int r = 0; r < 3; ++r) {
        P.biasK[r].x = (bk[2*i] + rh[3*i+r]) * LOG2E;
        P.biasK[r].y = bk1L;
    }
#pragma unroll
    for (int d = 0; d < 3; ++d) P.rwL[d] = rw[3*i+d] * LOG2E;
    P.wv0.x = wv[4*i];   P.wv0.y = wv[4*i+2];
    P.wv1.x = wv[4*i+1]; P.wv1.y = wv[4*i+3];
    P.bv.x  = bv[2*i];   P.bv.y  = bv[2*i+1];
    return P;
}

__device__ __forceinline__ void attn_strip(
    const v2f (&t)[3][6], const AttnW& P, v2f (&o)[4])
{
    v2f kk[3][6], vv[3][6];
#pragma unroll
    for (int r = 0; r < 3; ++r)
#pragma unroll
        for (int c = 0; c < 6; ++c) {
            v2f u0 = bc(t[r][c].x), u1 = bc(t[r][c].y);
            kk[r][c] = vfma(P.wk0, u0, vfma(P.wk1, u1, P.biasK[r]));
            vv[r][c] = vfma(P.wv0, u0, vfma(P.wv1, u1, P.bv));
        }
#pragma unroll
    for (int px = 0; px < 4; ++px) {
        v2f q = vfma(P.wq0, bc(t[1][px+1].x), vfma(P.wq1, bc(t[1][px+1].y), P.bq));
        v2f addv[3];
#pragma unroll
        for (int d = 0; d < 3; ++d) { addv[d].x = 0.f; addv[d].y = q.y * P.rwL[d]; }
        v2f s[9];
#pragma unroll
        for (int r = 0; r < 3; ++r)
#pragma unroll
            for (int d = 0; d < 3; ++d)
                s[r*3+d] = vfma(q, kk[r][px+d], addv[d]);
        v2f m = vmax2(vmax2(vmax2(vmax2(s[0], s[1]), vmax2(s[2], s[3])),
                            vmax2(vmax2(s[4], s[5]), vmax2(s[6], s[7]))), s[8]);
        v2f sum = bc(0.f), acc = bc(0.f);
#pragma unroll
        for (int r = 0; r < 3; ++r)
#pragma unroll
            for (int d = 0; d < 3; ++d) {
                v2f dd = s[r*3+d] - m;
                v2f e; e.x = EXP2F(dd.x); e.y = EXP2F(dd.y);
                sum += e;
                acc = vfma(e, vv[r][px+d], acc);
            }
        v2f rs; rs.x = frcp(sum.x); rs.y = frcp(sum.y);
        o[px] = acc * rs;
    }
}

__device__ __forceinline__ void write_pads(float* outp, int b2, int y, int x0)
{
    float4 z = make_float4(0.f, 0.f, 0.f, 0.f);
    if (x0 == 0) {
        int pb = b2 * PPLANE + y * PPITCH;
        *reinterpret_cast<float4*>(outp + pb)          = z;
        *reinterpret_cast<float4*>(outp + pb + PPLANE) = z;
    } else if (x0 == W - 4) {
        int pb = b2 * PPLANE + y * PPITCH + PXOFF + W;
        *reinterpret_cast<float4*>(outp + pb)          = z;
        *reinterpret_cast<float4*>(outp + pb + PPLANE) = z;
    }
}

// ---------------- stage bodies ----------------

__device__ __forceinline__ void attn_in_body(
    unsigned s, const float* __restrict__ x, float* outp, const AttnW& P)
{
    int x0 = (s & 127) * 4;
    int y  = (s >> 7) & 511;
    int b  = s >> 16;

    const float* xb = x + b * BSTRIDE;
    bool rowv[3] = { y > 0, true, y < H - 1 };
    int  yr[3]   = { y > 0 ? y - 1 : 0, y, y < H - 1 ? y + 1 : H - 1 };
    bool lv   = x0 > 0;
    bool rvld = x0 < W - 4;
    int  xl = lv ? x0 - 1 : 0;
    int  xr = rvld ? x0 + 4 : W - 1;

    v2f t[3][6];
#pragma unroll
    for (int r = 0; r < 3; ++r) {
        const float* p0 = xb + yr[r] * W;
        const float* p1 = p0 + PLANE;
        float4 a0 = *reinterpret_cast<const float4*>(p0 + x0);
        float4 a1 = *reinterpret_cast<const float4*>(p1 + x0);
        float u0[6] = { p0[xl], a0.x, a0.y, a0.z, a0.w, p0[xr] };
        float u1[6] = { p1[xl], a1.x, a1.y, a1.z, a1.w, p1[xr] };
        bool rv_ = rowv[r];
#pragma unroll
        for (int c = 0; c < 6; ++c) {
            bool ok = rv_ && (c > 0 || lv) && (c < 5 || rvld);
            t[r][c].x = ok ? reluf(u0[c]) : 0.f;
            t[r][c].y = ok ? reluf(u1[c]) : 0.f;
        }
    }

    v2f o[4];
    attn_strip(t, P, o);

    int ob = (b * 2) * PPLANE + y * PPITCH + x0 + PXOFF;
    *reinterpret_cast<float4*>(outp + ob)          = make_float4(o[0].x, o[1].x, o[2].x, o[3].x);
    *reinterpret_cast<float4*>(outp + ob + PPLANE) = make_float4(o[0].y, o[1].y, o[2].y, o[3].y);
    write_pads(outp, b * 2, y, x0);
}

template<int NRES, bool PADOUT>
__device__ __forceinline__ void attn_fast_body(
    unsigned s, const float* xp, float* outp,
    int oPlane, int oPitch, int oXoff,
    const float* res0, int aPlane, int aPitch, int aXoff,
    const float* res1, int cPlane, int cPitch, int cXoff,
    const AttnW& P)
{
    int x0 = (s & 127) * 4;
    int y  = (s >> 7) & 511;
    int b  = s >> 16;

    const float* xb0 = xp + (b * 2) * PPLANE + x0 + PXOFF;
    v2f t[3][6];
#pragma unroll
    for (int r = 0; r < 3; ++r) {
        int gy = y - 1 + r;
        bool ok = (unsigned)gy < (unsigned)H;
        int gyc = ok ? gy : y;
        const float* p0 = xb0 + gyc * PPITCH;
        const float* p1 = p0 + PPLANE;
        float4 a0 = *reinterpret_cast<const float4*>(p0);
        float4 a1 = *reinterpret_cast<const float4*>(p1);
        float e0l = p0[-1], e0r = p0[4];
        float e1l = p1[-1], e1r = p1[4];
        if (ok) {
            t[r][0].x=reluf(e0l);  t[r][0].y=reluf(e1l);
            t[r][1].x=reluf(a0.x); t[r][1].y=reluf(a1.x);
            t[r][2].x=reluf(a0.y); t[r][2].y=reluf(a1.y);
            t[r][3].x=reluf(a0.z); t[r][3].y=reluf(a1.z);
            t[r][4].x=reluf(a0.w); t[r][4].y=reluf(a1.w);
            t[r][5].x=reluf(e0r);  t[r][5].y=reluf(e1r);
        } else {
#pragma unroll
            for (int c = 0; c < 6; ++c) { t[r][c].x = 0.f; t[r][c].y = 0.f; }
        }
    }

    v2f o[4];
    attn_strip(t, P, o);

    if (NRES >= 1) {
        int rb = (b * 2) * aPlane + y * aPitch + x0 + aXoff;
        float4 ra = *reinterpret_cast<const float4*>(res0 + rb);
        float4 rbv = *reinterpret_cast<const float4*>(res0 + rb + aPlane);
        o[0].x+=ra.x; o[1].x+=ra.y; o[2].x+=ra.z; o[3].x+=ra.w;
        o[0].y+=rbv.x; o[1].y+=rbv.y; o[2].y+=rbv.z; o[3].y+=rbv.w;
    }
    if (NRES >= 2) {
        int rb = (b * 2) * cPlane + y * cPitch + x0 + cXoff;
        float4 ra = *reinterpret_cast<const float4*>(res1 + rb);
        float4 rbv = *reinterpret_cast<const float4*>(res1 + rb + cPlane);
        o[0].x+=ra.x; o[1].x+=ra.y; o[2].x+=ra.z; o[3].x+=ra.w;
        o[0].y+=rbv.x; o[1].y+=rbv.y; o[2].y+=rbv.z; o[3].y+=rbv.w;
    }

    int ob = (b * 2) * oPlane + y * oPitch + x0 + oXoff;
    *reinterpret_cast<float4*>(outp + ob)          = make_float4(o[0].x, o[1].x, o[2].x, o[3].x);
    *reinterpret_cast<float4*>(outp + ob + oPlane) = make_float4(o[0].y, o[1].y, o[2].y, o[3].y);
    if (PADOUT) write_pads(outp, b * 2, y, x0);
}

__device__ __forceinline__ void conv_body(
    unsigned s, const float* u, const float (&w)[18], float cb0, float* o)
{
    int x0 = (s & 127) * 4;
    int y  = (s >> 7) & 511;
    int b  = s >> 16;

    int yy[3];
#pragma unroll
    for (int i = 0; i < 3; ++i) {
        int t = y + i - 1;
        if (t < 0) t = -t;
        if (t > H - 1) t = 2 * (H - 1) - t;
        yy[i] = t;
    }
    int xl = x0 - 1; if (xl < 0) xl = 1;
    int xr = x0 + 4; if (xr > W - 1) xr = 2 * (W - 1) - xr;

    float acc[4] = { cb0, cb0, cb0, cb0 };
#pragma unroll
    for (int c = 0; c < 2; ++c) {
        const float* up = u + b * BSTRIDE + c * PLANE;
#pragma unroll
        for (int i = 0; i < 3; ++i) {
            const float* row = up + yy[i] * W;
            float4 a = *reinterpret_cast<const float4*>(row + x0);
            float t[6] = { row[xl], a.x, a.y, a.z, a.w, row[xr] };
#pragma unroll
            for (int j = 0; j < 3; ++j) {
                float wc = w[c * 9 + i * 3 + j];
#pragma unroll
                for (int px = 0; px < 4; ++px)
                    acc[px] = fmaf(t[px + j], wc, acc[px]);
            }
        }
    }
    float4 ov;
    ov.x = frcp(1.f + EXP2F(-acc[0] * LOG2E));
    ov.y = frcp(1.f + EXP2F(-acc[1] * LOG2E));
    ov.z = frcp(1.f + EXP2F(-acc[2] * LOG2E));
    ov.w = frcp(1.f + EXP2F(-acc[3] * LOG2E));
    *reinterpret_cast<float4*>(o + b * PLANE + y * W + x0) = ov;
}

__device__ __forceinline__ void up_body(unsigned p, const float* o, float* up)
{
    int b  = p >> 18;
    int y  = (p >> 8) & 1023;
    int x0 = (p & 255) * 4;

    const float scale = 511.0f / 1023.0f;
    float fy = y * scale;
    int y0 = (int)fy;
    float wy = fy - y0;
    int y1 = min(y0 + 1, H - 1);

    const float* ob = o + b * PLANE;
    const float* row0 = ob + y0 * W;
    const float* row1 = ob + y1 * W;

    float4 ov;
    float* ovp = &ov.x;
#pragma unroll
    for (int j = 0; j < 4; ++j) {
        float fx = (x0 + j) * scale;
        int xi = (int)fx;
        float wx = fx - xi;
        int xi1 = min(xi + 1, W - 1);
        float v00 = row0[xi], v01 = row0[xi1];
        float v10 = row1[xi], v11 = row1[xi1];
        float top = fmaf(v01 - v00, wx, v00);
        float bot = fmaf(v11 - v10, wx, v10);
        ovp[j] = fmaf(bot - top, wy, top);
    }
    *reinterpret_cast<float4*>(up + ((long)b << 20) + y * 1024 + x0) = ov;
}

// ---------------- kernels (round-6 structure + XCD swizzle) ----------------

__global__ __launch_bounds__(256) void attn_in_kernel(
    const float* __restrict__ xA, const float* __restrict__ xB,
    float* outA, float* outB,
    const float* __restrict__ wq, const float* __restrict__ bq,
    const float* __restrict__ wk, const float* __restrict__ bk,
    const float* __restrict__ wv, const float* __restrict__ bv,
    const float* __restrict__ rh, const float* __restrict__ rw,
    int piA, int piB)
{
    unsigned wid = swz8(blockIdx.x, 4096);   // XCD 0-3 -> in1, XCD 4-7 -> in2
    bool second = wid >= 2048;
    AttnW P = load_w(wq, bq, wk, bk, wv, bv, rh, rw, second ? piB : piA);
    unsigned s = (second ? wid - 2048 : wid) * 256u + threadIdx.x;
    attn_in_body(s, second ? xB : xA, second ? outB : outA, P);
}

template<int NRES, bool PADOUT>
__global__ __launch_bounds__(256) void attn_fast_kernel(
    const float* xp, float* outp, int oPlane, int oPitch, int oXoff,
    const float* res0, int aPlane, int aPitch, int aXoff,
    const float* res1, int cPlane, int cPitch, int cXoff,
    const float* __restrict__ wq, const float* __restrict__ bq,
    const float* __restrict__ wk, const float* __restrict__ bk,
    const float* __restrict__ wv, const float* __restrict__ bv,
    const float* __restrict__ rh, const float* __restrict__ rw, int pi)
{
    AttnW P = load_w(wq, bq, wk, bk, wv, bv, rh, rw, pi);
    unsigned s = swz8(blockIdx.x, 2048) * 256u + threadIdx.x;  // 1 batch per XCD
    attn_fast_body<NRES,PADOUT>(s, xp, outp, oPlane, oPitch, oXoff,
        res0, aPlane, aPitch, aXoff, res1, cPlane, cPitch, cXoff, P);
}

__global__ __launch_bounds__(256) void conv_sig4_kernel(
    const float* u, const float* __restrict__ cw, const float* __restrict__ cb,
    float* o)
{
    float w18[18];
#pragma unroll
    for (int i = 0; i < 18; ++i) w18[i] = cw[i];
    conv_body(swz8(blockIdx.x, 2048) * 256u + threadIdx.x, u, w18, cb[0], o);
}

__global__ __launch_bounds__(256) void upsample4_kernel(const float* o, float* up)
{
    up_body(swz8(blockIdx.x, 8192) * 256u + threadIdx.x, o, up);
}

extern "C" void kernel_launch(void* const* d_in, const int* in_sizes, int n_in,
                              void* d_out, int out_size, void* d_ws, size_t ws_size,
                              hipStream_t stream) {
    const float* in1 = (const float*)d_in[0];
    const float* in2 = (const float*)d_in[1];
    const float* wq  = (const float*)d_in[2];
    const float* bq  = (const float*)d_in[3];
    const float* wk  = (const float*)d_in[4];
    const float* bk  = (const float*)d_in[5];
    const float* wv  = (const float*)d_in[6];
    const float* bv  = (const float*)d_in[7];
    const float* rh  = (const float*)d_in[8];
    const float* rw  = (const float*)d_in[9];
    const float* cw  = (const float*)d_in[10];
    const float* cb  = (const float*)d_in[11];

    float* out = (float*)d_out;
    float* A  = out;              // padded tensor 0
    float* Bb = out + PBUF;       // padded tensor 1 (ends at 8,519,680 <= 10,485,760)
    float* C  = (float*)d_ws;     // unpadded scratch
    (void)ws_size; (void)out_size; (void)n_in; (void)in_sizes;

    dim3 blk(256);

    // K1 (batched): t1 = attn0(relu(in1)) -> A ; t3 = attn2(relu(in2)) -> B
    attn_in_kernel<<<4096, blk, 0, stream>>>(in1, in2, A, Bb,
        wq, bq, wk, bk, wv, bv, rh, rw, 0, 2);
    // K2: r1 = attn1(relu(t1)) + in1 -> C
    attn_fast_kernel<1,false><<<2048, blk, 0, stream>>>(A, C, PLANE, W, 0,
        in1, PLANE, W, 0, nullptr, 0, 0, 0,
        wq, bq, wk, bk, wv, bv, rh, rw, 1);
    // K3: s = attn3(relu(t3)) + in2 + r1 -> A (padded)
    attn_fast_kernel<2,true><<<2048, blk, 0, stream>>>(Bb, A, PPLANE, PPITCH, PXOFF,
        in2, PLANE, W, 0, C, PLANE, W, 0,
        wq, bq, wk, bk, wv, bv, rh, rw, 3);
    // K4: t5 = attn4(relu(s)) -> B (padded)
    attn_fast_kernel<0,true><<<2048, blk, 0, stream>>>(A, Bb, PPLANE, PPITCH, PXOFF,
        nullptr, 0, 0, 0, nullptr, 0, 0, 0,
        wq, bq, wk, bk, wv, bv, rh, rw, 4);
    // K5: u = attn5(relu(t5)) + s -> C  (residual s is padded)
    attn_fast_kernel<1,false><<<2048, blk, 0, stream>>>(Bb, C, PLANE, W, 0,
        A, PPLANE, PPITCH, PXOFF, nullptr, 0, 0, 0,
        wq, bq, wk, bk, wv, bv, rh, rw, 5);
    // K6: o = sigmoid(conv3x3(reflect_pad(u))) -> out[0:2M]
    conv_sig4_kernel<<<2048, blk, 0, stream>>>(C, cw, cb, out);
    // K7: up = bilinear2x(o) -> out[2M:]
    upsample4_kernel<<<8192, blk, 0, stream>>>(out, out + NPIX);
}

// Round 9
// 105.226 us; speedup vs baseline: 3.7223x; 1.0809x over previous
//
#include <hip/hip_runtime.h>

#if __has_builtin(__builtin_amdgcn_exp2f)
#define EXP2F(x) __builtin_amdgcn_exp2f(x)
#else
#define EXP2F(x) exp2f(x)
#endif

typedef float v2f __attribute__((ext_vector_type(2)));

constexpr int B = 8, H = 512, W = 512;
constexpr int PLANE = H * W;              // 262144
constexpr int BSTRIDE = 2 * PLANE;
constexpr int NPIX = B * PLANE;           // 2097152
constexpr int PPITCH = 520;               // padded row pitch (4 left, 4 right)
constexpr int PXOFF  = 4;
constexpr int PPLANE = H * PPITCH;        // 266240
constexpr int PBUF   = 16 * PPLANE;       // 4,259,840 floats per padded tensor
constexpr float LOG2E = 1.4426950408889634f;

__device__ __forceinline__ float reluf(float v) { return v > 0.f ? v : 0.f; }
__device__ __forceinline__ float frcp(float v) { return __builtin_amdgcn_rcpf(v); }
__device__ __forceinline__ v2f vfma(v2f a, v2f b, v2f c) { return __builtin_elementwise_fma(a, b, c); }
__device__ __forceinline__ v2f vmax2(v2f a, v2f b) { return __builtin_elementwise_max(a, b); }
__device__ __forceinline__ v2f bc(float x) { v2f r; r.x = x; r.y = x; return r; }

// XCD-aware bijective work swizzle (8 XCDs, nwg % 8 == 0)
__device__ __forceinline__ unsigned swz8(unsigned bid, unsigned nwg)
{
    return (bid & 7u) * (nwg >> 3) + (bid >> 3);
}

struct AttnW {
    v2f wq0, wq1, bq;
    v2f wk0, wk1;
    v2f biasK[3];              // ((bk0+rh[r])*L, bk1*L)
    float rwL[3];              // rw[d]*L (ch1 additive)
    v2f wv0, wv1, bv;
};

__device__ __forceinline__ AttnW load_w(
    const float* wq, const float* bq, const float* wk, const float* bk,
    const float* wv, const float* bv, const float* rh, const float* rw, int i)
{
    AttnW P;
    P.wq0.x = wq[4*i];   P.wq0.y = wq[4*i+2];
    P.wq1.x = wq[4*i+1]; P.wq1.y = wq[4*i+3];
    P.bq.x  = bq[2*i];   P.bq.y  = bq[2*i+1];
    P.wk0.x = wk[4*i]   * LOG2E; P.wk0.y = wk[4*i+2] * LOG2E;
    P.wk1.x = wk[4*i+1] * LOG2E; P.wk1.y = wk[4*i+3] * LOG2E;
    float bk1L = bk[2*i+1] * LOG2E;
#pragma unroll
    for (int r = 0; r < 3; ++r) {
        P.biasK[r].x = (bk[2*i] + rh[3*i+r]) * LOG2E;
        P.biasK[r].y = bk1L;
    }
#pragma unroll
    for (int d = 0; d < 3; ++d) P.rwL[d] = rw[3*i+d] * LOG2E;
    P.wv0.x = wv[4*i];   P.wv0.y = wv[4*i+2];
    P.wv1.x = wv[4*i+1]; P.wv1.y = wv[4*i+3];
    P.bv.x  = bv[2*i];   P.bv.y  = bv[2*i+1];
    return P;
}

__device__ __forceinline__ void attn_strip(
    const v2f (&t)[3][6], const AttnW& P, v2f (&o)[4])
{
    v2f kk[3][6], vv[3][6];
#pragma unroll
    for (int r = 0; r < 3; ++r)
#pragma unroll
        for (int c = 0; c < 6; ++c) {
            v2f u0 = bc(t[r][c].x), u1 = bc(t[r][c].y);
            kk[r][c] = vfma(P.wk0, u0, vfma(P.wk1, u1, P.biasK[r]));
            vv[r][c] = vfma(P.wv0, u0, vfma(P.wv1, u1, P.bv));
        }
#pragma unroll
    for (int px = 0; px < 4; ++px) {
        v2f q = vfma(P.wq0, bc(t[1][px+1].x), vfma(P.wq1, bc(t[1][px+1].y), P.bq));
        v2f addv[3];
#pragma unroll
        for (int d = 0; d < 3; ++d) { addv[d].x = 0.f; addv[d].y = q.y * P.rwL[d]; }
        v2f s[9];
#pragma unroll
        for (int r = 0; r < 3; ++r)
#pragma unroll
            for (int d = 0; d < 3; ++d)
                s[r*3+d] = vfma(q, kk[r][px+d], addv[d]);
        v2f m = vmax2(vmax2(vmax2(vmax2(s[0], s[1]), vmax2(s[2], s[3])),
                            vmax2(vmax2(s[4], s[5]), vmax2(s[6], s[7]))), s[8]);
        v2f sum = bc(0.f), acc = bc(0.f);
#pragma unroll
        for (int r = 0; r < 3; ++r)
#pragma unroll
            for (int d = 0; d < 3; ++d) {
                v2f dd = s[r*3+d] - m;
                v2f e; e.x = EXP2F(dd.x); e.y = EXP2F(dd.y);
                sum += e;
                acc = vfma(e, vv[r][px+d], acc);
            }
        v2f rs; rs.x = frcp(sum.x); rs.y = frcp(sum.y);
        o[px] = acc * rs;
    }
}

__device__ __forceinline__ void write_pads(float* outp, int b2, int y, int x0)
{
    float4 z = make_float4(0.f, 0.f, 0.f, 0.f);
    if (x0 == 0) {
        int pb = b2 * PPLANE + y * PPITCH;
        *reinterpret_cast<float4*>(outp + pb)          = z;
        *reinterpret_cast<float4*>(outp + pb + PPLANE) = z;
    } else if (x0 == W - 4) {
        int pb = b2 * PPLANE + y * PPITCH + PXOFF + W;
        *reinterpret_cast<float4*>(outp + pb)          = z;
        *reinterpret_cast<float4*>(outp + pb + PPLANE) = z;
    }
}

// ---- neighborhood loaders (relu'd, zero outside image) ----

__device__ __forceinline__ void load_t_unpadded(
    unsigned s, const float* __restrict__ x, v2f (&t)[3][6])
{
    int x0 = (s & 127) * 4;
    int y  = (s >> 7) & 511;
    int b  = s >> 16;

    const float* xb = x + b * BSTRIDE;
    bool rowv[3] = { y > 0, true, y < H - 1 };
    int  yr[3]   = { y > 0 ? y - 1 : 0, y, y < H - 1 ? y + 1 : H - 1 };
    bool lv   = x0 > 0;
    bool rvld = x0 < W - 4;
    int  xl = lv ? x0 - 1 : 0;
    int  xr = rvld ? x0 + 4 : W - 1;

#pragma unroll
    for (int r = 0; r < 3; ++r) {
        const float* p0 = xb + yr[r] * W;
        const float* p1 = p0 + PLANE;
        float4 a0 = *reinterpret_cast<const float4*>(p0 + x0);
        float4 a1 = *reinterpret_cast<const float4*>(p1 + x0);
        float u0[6] = { p0[xl], a0.x, a0.y, a0.z, a0.w, p0[xr] };
        float u1[6] = { p1[xl], a1.x, a1.y, a1.z, a1.w, p1[xr] };
        bool rv_ = rowv[r];
#pragma unroll
        for (int c = 0; c < 6; ++c) {
            bool ok = rv_ && (c > 0 || lv) && (c < 5 || rvld);
            t[r][c].x = ok ? reluf(u0[c]) : 0.f;
            t[r][c].y = ok ? reluf(u1[c]) : 0.f;
        }
    }
}

__device__ __forceinline__ void load_t_padded(
    unsigned s, const float* __restrict__ xp, v2f (&t)[3][6])
{
    int x0 = (s & 127) * 4;
    int y  = (s >> 7) & 511;
    int b  = s >> 16;

    const float* xb0 = xp + (b * 2) * PPLANE + x0 + PXOFF;
#pragma unroll
    for (int r = 0; r < 3; ++r) {
        int gy = y - 1 + r;
        bool ok = (unsigned)gy < (unsigned)H;   // wave-uniform
        int gyc = ok ? gy : y;
        const float* p0 = xb0 + gyc * PPITCH;
        const float* p1 = p0 + PPLANE;
        float4 a0 = *reinterpret_cast<const float4*>(p0);
        float4 a1 = *reinterpret_cast<const float4*>(p1);
        float e0l = p0[-1], e0r = p0[4];
        float e1l = p1[-1], e1r = p1[4];
        if (ok) {
            t[r][0].x=reluf(e0l);  t[r][0].y=reluf(e1l);
            t[r][1].x=reluf(a0.x); t[r][1].y=reluf(a1.x);
            t[r][2].x=reluf(a0.y); t[r][2].y=reluf(a1.y);
            t[r][3].x=reluf(a0.z); t[r][3].y=reluf(a1.z);
            t[r][4].x=reluf(a0.w); t[r][4].y=reluf(a1.w);
            t[r][5].x=reluf(e0r);  t[r][5].y=reluf(e1r);
        } else {
#pragma unroll
            for (int c = 0; c < 6; ++c) { t[r][c].x = 0.f; t[r][c].y = 0.f; }
        }
    }
}

// ---------------- kernels ----------------

// K1 (batched): t1 = attn0(relu(in1)) -> A ; t3 = attn2(relu(in2)) -> B (padded)
__global__ __launch_bounds__(256) void attn_in_kernel(
    const float* __restrict__ xA, const float* __restrict__ xB,
    float* outA, float* outB,
    const float* __restrict__ wq, const float* __restrict__ bq,
    const float* __restrict__ wk, const float* __restrict__ bk,
    const float* __restrict__ wv, const float* __restrict__ bv,
    const float* __restrict__ rh, const float* __restrict__ rw,
    int piA, int piB)
{
    unsigned wid = swz8(blockIdx.x, 4096);
    bool second = wid >= 2048;
    AttnW P = load_w(wq, bq, wk, bk, wv, bv, rh, rw, second ? piB : piA);
    unsigned s = (second ? wid - 2048 : wid) * 256u + threadIdx.x;

    v2f t[3][6];
    load_t_unpadded(s, second ? xB : xA, t);
    v2f o[4];
    attn_strip(t, P, o);

    int x0 = (s & 127) * 4;
    int y  = (s >> 7) & 511;
    int b  = s >> 16;
    float* outp = second ? outB : outA;
    int ob = (b * 2) * PPLANE + y * PPITCH + x0 + PXOFF;
    *reinterpret_cast<float4*>(outp + ob)          = make_float4(o[0].x, o[1].x, o[2].x, o[3].x);
    *reinterpret_cast<float4*>(outp + ob + PPLANE) = make_float4(o[0].y, o[1].y, o[2].y, o[3].y);
    write_pads(outp, b * 2, y, x0);
}

// K23 (fused): r1 = attn1(t1)+in1 ; s = attn3(t3)+in2+r1 -> C (unpadded)
__global__ __launch_bounds__(256) void attn_fused23_kernel(
    const float* __restrict__ A, const float* __restrict__ Bb,
    const float* __restrict__ in1, const float* __restrict__ in2,
    float* __restrict__ C,
    const float* __restrict__ wq, const float* __restrict__ bq,
    const float* __restrict__ wk, const float* __restrict__ bk,
    const float* __restrict__ wv, const float* __restrict__ bv,
    const float* __restrict__ rh, const float* __restrict__ rw)
{
    unsigned s = swz8(blockIdx.x, 2048) * 256u + threadIdx.x;
    int x0 = (s & 127) * 4;
    int y  = (s >> 7) & 511;
    int b  = s >> 16;
    int base0 = b * BSTRIDE + y * W + x0;
    int base1 = base0 + PLANE;

    v2f t[3][6];
    v2f o1[4], o2[4];

    {
        AttnW P1 = load_w(wq, bq, wk, bk, wv, bv, rh, rw, 1);
        load_t_padded(s, A, t);
        attn_strip(t, P1, o1);
        float4 ra = *reinterpret_cast<const float4*>(in1 + base0);
        float4 rb = *reinterpret_cast<const float4*>(in1 + base1);
        o1[0].x += ra.x; o1[1].x += ra.y; o1[2].x += ra.z; o1[3].x += ra.w;
        o1[0].y += rb.x; o1[1].y += rb.y; o1[2].y += rb.z; o1[3].y += rb.w;
    }
    {
        AttnW P3 = load_w(wq, bq, wk, bk, wv, bv, rh, rw, 3);
        load_t_padded(s, Bb, t);
        attn_strip(t, P3, o2);
        float4 ra = *reinterpret_cast<const float4*>(in2 + base0);
        float4 rb = *reinterpret_cast<const float4*>(in2 + base1);
        o2[0].x += ra.x + o1[0].x; o2[1].x += ra.y + o1[1].x;
        o2[2].x += ra.z + o1[2].x; o2[3].x += ra.w + o1[3].x;
        o2[0].y += rb.x + o1[0].y; o2[1].y += rb.y + o1[1].y;
        o2[2].y += rb.z + o1[2].y; o2[3].y += rb.w + o1[3].y;
    }

    *reinterpret_cast<float4*>(C + base0) = make_float4(o2[0].x, o2[1].x, o2[2].x, o2[3].x);
    *reinterpret_cast<float4*>(C + base1) = make_float4(o2[0].y, o2[1].y, o2[2].y, o2[3].y);
}

// K4: t5 = attn4(relu(s)) -> B (padded); s read unpadded with bounds checks
__global__ __launch_bounds__(256) void attn4_kernel(
    const float* __restrict__ C, float* __restrict__ Bb,
    const float* __restrict__ wq, const float* __restrict__ bq,
    const float* __restrict__ wk, const float* __restrict__ bk,
    const float* __restrict__ wv, const float* __restrict__ bv,
    const float* __restrict__ rh, const float* __restrict__ rw)
{
    unsigned s = swz8(blockIdx.x, 2048) * 256u + threadIdx.x;
    AttnW P = load_w(wq, bq, wk, bk, wv, bv, rh, rw, 4);
    v2f t[3][6];
    load_t_unpadded(s, C, t);
    v2f o[4];
    attn_strip(t, P, o);

    int x0 = (s & 127) * 4;
    int y  = (s >> 7) & 511;
    int b  = s >> 16;
    int ob = (b * 2) * PPLANE + y * PPITCH + x0 + PXOFF;
    *reinterpret_cast<float4*>(Bb + ob)          = make_float4(o[0].x, o[1].x, o[2].x, o[3].x);
    *reinterpret_cast<float4*>(Bb + ob + PPLANE) = make_float4(o[0].y, o[1].y, o[2].y, o[3].y);
    write_pads(Bb, b * 2, y, x0);
}

// K5: u = attn5(relu(t5)) + s -> C in-place (each thread touches only its own pixels)
__global__ __launch_bounds__(256) void attn5_kernel(
    const float* __restrict__ Bb, float* __restrict__ C,
    const float* __restrict__ wq, const float* __restrict__ bq,
    const float* __restrict__ wk, const float* __restrict__ bk,
    const float* __restrict__ wv, const float* __restrict__ bv,
    const float* __restrict__ rh, const float* __restrict__ rw)
{
    unsigned s = swz8(blockIdx.x, 2048) * 256u + threadIdx.x;
    AttnW P = load_w(wq, bq, wk, bk, wv, bv, rh, rw, 5);
    v2f t[3][6];
    load_t_padded(s, Bb, t);
    v2f o[4];
    attn_strip(t, P, o);

    int x0 = (s & 127) * 4;
    int y  = (s >> 7) & 511;
    int b  = s >> 16;
    int base0 = b * BSTRIDE + y * W + x0;
    int base1 = base0 + PLANE;
    float4 ra = *reinterpret_cast<const float4*>(C + base0);
    float4 rb = *reinterpret_cast<const float4*>(C + base1);
    o[0].x += ra.x; o[1].x += ra.y; o[2].x += ra.z; o[3].x += ra.w;
    o[0].y += rb.x; o[1].y += rb.y; o[2].y += rb.z; o[3].y += rb.w;
    *reinterpret_cast<float4*>(C + base0) = make_float4(o[0].x, o[1].x, o[2].x, o[3].x);
    *reinterpret_cast<float4*>(C + base1) = make_float4(o[0].y, o[1].y, o[2].y, o[3].y);
}

// K6: reflect-pad 3x3 conv (2ch->1ch) + sigmoid
__global__ __launch_bounds__(256) void conv_sig4_kernel(
    const float* __restrict__ u,
    const float* __restrict__ cw, const float* __restrict__ cb,
    float* __restrict__ o)
{
    unsigned s = swz8(blockIdx.x, 2048) * 256u + threadIdx.x;
    int x0 = (s & 127) * 4;
    int y  = (s >> 7) & 511;
    int b  = s >> 16;

    float w[18];
#pragma unroll
    for (int i = 0; i < 18; ++i) w[i] = cw[i];

    int yy[3];
#pragma unroll
    for (int i = 0; i < 3; ++i) {
        int t = y + i - 1;
        if (t < 0) t = -t;
        if (t > H - 1) t = 2 * (H - 1) - t;
        yy[i] = t;
    }
    int xl = x0 - 1; if (xl < 0) xl = 1;
    int xr = x0 + 4; if (xr > W - 1) xr = 2 * (W - 1) - xr;

    float acc[4] = { cb[0], cb[0], cb[0], cb[0] };
#pragma unroll
    for (int c = 0; c < 2; ++c) {
        const float* up = u + b * BSTRIDE + c * PLANE;
#pragma unroll
        for (int i = 0; i < 3; ++i) {
            const float* row = up + yy[i] * W;
            float4 a = *reinterpret_cast<const float4*>(row + x0);
            float t[6] = { row[xl], a.x, a.y, a.z, a.w, row[xr] };
#pragma unroll
            for (int j = 0; j < 3; ++j) {
                float wc = w[c * 9 + i * 3 + j];
#pragma unroll
                for (int px = 0; px < 4; ++px)
                    acc[px] = fmaf(t[px + j], wc, acc[px]);
            }
        }
    }
    float4 ov;
    ov.x = frcp(1.f + EXP2F(-acc[0] * LOG2E));
    ov.y = frcp(1.f + EXP2F(-acc[1] * LOG2E));
    ov.z = frcp(1.f + EXP2F(-acc[2] * LOG2E));
    ov.w = frcp(1.f + EXP2F(-acc[3] * LOG2E));
    *reinterpret_cast<float4*>(o + b * PLANE + y * W + x0) = ov;
}

// K7: 2x bilinear upsample (linspace(0,511,1024) grid)
__global__ __launch_bounds__(256) void upsample4_kernel(
    const float* __restrict__ o, float* __restrict__ up)
{
    unsigned p = swz8(blockIdx.x, 8192) * 256u + threadIdx.x;
    int b  = p >> 18;
    int y  = (p >> 8) & 1023;
    int x0 = (p & 255) * 4;

    const float scale = 511.0f / 1023.0f;
    float fy = y * scale;
    int y0 = (int)fy;
    float wy = fy - y0;
    int y1 = min(y0 + 1, H - 1);

    const float* ob = o + b * PLANE;
    const float* row0 = ob + y0 * W;
    const float* row1 = ob + y1 * W;

    float4 ov;
    float* ovp = &ov.x;
#pragma unroll
    for (int j = 0; j < 4; ++j) {
        float fx = (x0 + j) * scale;
        int xi = (int)fx;
        float wx = fx - xi;
        int xi1 = min(xi + 1, W - 1);
        float v00 = row0[xi], v01 = row0[xi1];
        float v10 = row1[xi], v11 = row1[xi1];
        float top = fmaf(v01 - v00, wx, v00);
        float bot = fmaf(v11 - v10, wx, v10);
        ovp[j] = fmaf(bot - top, wy, top);
    }
    *reinterpret_cast<float4*>(up + ((long)b << 20) + y * 1024 + x0) = ov;
}

extern "C" void kernel_launch(void* const* d_in, const int* in_sizes, int n_in,
                              void* d_out, int out_size, void* d_ws, size_t ws_size,
                              hipStream_t stream) {
    const float* in1 = (const float*)d_in[0];
    const float* in2 = (const float*)d_in[1];
    const float* wq  = (const float*)d_in[2];
    const float* bq  = (const float*)d_in[3];
    const float* wk  = (const float*)d_in[4];
    const float* bk  = (const float*)d_in[5];
    const float* wv  = (const float*)d_in[6];
    const float* bv  = (const float*)d_in[7];
    const float* rh  = (const float*)d_in[8];
    const float* rw  = (const float*)d_in[9];
    const float* cw  = (const float*)d_in[10];
    const float* cb  = (const float*)d_in[11];

    float* out = (float*)d_out;
    float* A  = out;              // padded t1   (dead after K23; K6 overwrites)
    float* Bb = out + PBUF;       // padded t3 then t5 (dead after K5; K7 overwrites)
    float* C  = (float*)d_ws;     // unpadded: s, then u (in-place)
    (void)ws_size; (void)out_size; (void)n_in; (void)in_sizes;

    dim3 blk(256);

    // K1: t1 = attn0(relu(in1)) -> A ; t3 = attn2(relu(in2)) -> B
    attn_in_kernel<<<4096, blk, 0, stream>>>(in1, in2, A, Bb,
        wq, bq, wk, bk, wv, bv, rh, rw, 0, 2);
    // K23: s = attn3(relu(t3)) + in2 + (attn1(relu(t1)) + in1) -> C
    attn_fused23_kernel<<<2048, blk, 0, stream>>>(A, Bb, in1, in2, C,
        wq, bq, wk, bk, wv, bv, rh, rw);
    // K4: t5 = attn4(relu(s)) -> B
    attn4_kernel<<<2048, blk, 0, stream>>>(C, Bb,
        wq, bq, wk, bk, wv, bv, rh, rw);
    // K5: u = attn5(relu(t5)) + s -> C (in-place)
    attn5_kernel<<<2048, blk, 0, stream>>>(Bb, C,
        wq, bq, wk, bk, wv, bv, rh, rw);
    // K6: o = sigmoid(conv3x3(reflect_pad(u))) -> out[0:2M]
    conv_sig4_kernel<<<2048, blk, 0, stream>>>(C, cw, cb, out);
    // K7: up = bilinear2x(o) -> out[2M:]
    upsample4_kernel<<<8192, blk, 0, stream>>>(out, out + NPIX);
}

// Round 10
// 99.795 us; speedup vs baseline: 3.9248x; 1.0544x over previous
//
#include <hip/hip_runtime.h>

#if __has_builtin(__builtin_amdgcn_exp2f)
#define EXP2F(x) __builtin_amdgcn_exp2f(x)
#else
#define EXP2F(x) exp2f(x)
#endif

typedef float v2f __attribute__((ext_vector_type(2)));
typedef _Float16 h2v __attribute__((ext_vector_type(2)));   // 4B
typedef _Float16 h4v __attribute__((ext_vector_type(4)));   // 8B

constexpr int B = 8, H = 512, W = 512;
constexpr int PLANE = H * W;              // 262144
constexpr int BSTRIDE = 2 * PLANE;
constexpr int NPIX = B * PLANE;           // 2097152
constexpr int PPITCH = 520;               // padded row pitch (4 left, 4 right)
constexpr int PXOFF  = 4;
constexpr int PPLANE = H * PPITCH;        // 266240 halves per (b,ch) plane
constexpr int PBUF   = 16 * PPLANE;       // 4,259,840 halves per padded tensor (8.5MB)
constexpr float LOG2E = 1.4426950408889634f;

__device__ __forceinline__ float reluf(float v) { return v > 0.f ? v : 0.f; }
__device__ __forceinline__ float frcp(float v) { return __builtin_amdgcn_rcpf(v); }
__device__ __forceinline__ v2f vfma(v2f a, v2f b, v2f c) { return __builtin_elementwise_fma(a, b, c); }
__device__ __forceinline__ v2f vmax2(v2f a, v2f b) { return __builtin_elementwise_max(a, b); }
__device__ __forceinline__ v2f bc(float x) { v2f r; r.x = x; r.y = x; return r; }

// XCD-aware bijective work swizzle (8 XCDs, nwg % 8 == 0)
__device__ __forceinline__ unsigned swz8(unsigned bid, unsigned nwg)
{
    return (bid & 7u) * (nwg >> 3) + (bid >> 3);
}

struct AttnW {
    v2f wq0, wq1, bq;
    v2f wk0, wk1;
    v2f biasK[3];              // ((bk0+rh[r])*L, bk1*L)
    float rwL[3];              // rw[d]*L (ch1 additive)
    v2f wv0, wv1, bv;
};

__device__ __forceinline__ AttnW load_w(
    const float* wq, const float* bq, const float* wk, const float* bk,
    const float* wv, const float* bv, const float* rh, const float* rw, int i)
{
    AttnW P;
    P.wq0.x = wq[4*i];   P.wq0.y = wq[4*i+2];
    P.wq1.x = wq[4*i+1]; P.wq1.y = wq[4*i+3];
    P.bq.x  = bq[2*i];   P.bq.y  = bq[2*i+1];
    P.wk0.x = wk[4*i]   * LOG2E; P.wk0.y = wk[4*i+2] * LOG2E;
    P.wk1.x = wk[4*i+1] * LOG2E; P.wk1.y = wk[4*i+3] * LOG2E;
    float bk1L = bk[2*i+1] * LOG2E;
#pragma unroll
    for (int r = 0; r < 3; ++r) {
        P.biasK[r].x = (bk[2*i] + rh[3*i+r]) * LOG2E;
        P.biasK[r].y = bk1L;
    }
#pragma unroll
    for (int d = 0; d < 3; ++d) P.rwL[d] = rw[3*i+d] * LOG2E;
    P.wv0.x = wv[4*i];   P.wv0.y = wv[4*i+2];
    P.wv1.x = wv[4*i+1]; P.wv1.y = wv[4*i+3];
    P.bv.x  = bv[2*i];   P.bv.y  = bv[2*i+1];
    return P;
}

__device__ __forceinline__ void attn_strip(
    const v2f (&t)[3][6], const AttnW& P, v2f (&o)[4])
{
    v2f kk[3][6], vv[3][6];
#pragma unroll
    for (int r = 0; r < 3; ++r)
#pragma unroll
        for (int c = 0; c < 6; ++c) {
            v2f u0 = bc(t[r][c].x), u1 = bc(t[r][c].y);
            kk[r][c] = vfma(P.wk0, u0, vfma(P.wk1, u1, P.biasK[r]));
            vv[r][c] = vfma(P.wv0, u0, vfma(P.wv1, u1, P.bv));
        }
#pragma unroll
    for (int px = 0; px < 4; ++px) {
        v2f q = vfma(P.wq0, bc(t[1][px+1].x), vfma(P.wq1, bc(t[1][px+1].y), P.bq));
        v2f addv[3];
#pragma unroll
        for (int d = 0; d < 3; ++d) { addv[d].x = 0.f; addv[d].y = q.y * P.rwL[d]; }
        v2f s[9];
#pragma unroll
        for (int r = 0; r < 3; ++r)
#pragma unroll
            for (int d = 0; d < 3; ++d)
                s[r*3+d] = vfma(q, kk[r][px+d], addv[d]);
        v2f m = vmax2(vmax2(vmax2(vmax2(s[0], s[1]), vmax2(s[2], s[3])),
                            vmax2(vmax2(s[4], s[5]), vmax2(s[6], s[7]))), s[8]);
        v2f sum = bc(0.f), acc = bc(0.f);
#pragma unroll
        for (int r = 0; r < 3; ++r)
#pragma unroll
            for (int d = 0; d < 3; ++d) {
                v2f dd = s[r*3+d] - m;
                v2f e; e.x = EXP2F(dd.x); e.y = EXP2F(dd.y);
                sum += e;
                acc = vfma(e, vv[r][px+d], acc);
            }
        v2f rs; rs.x = frcp(sum.x); rs.y = frcp(sum.y);
        o[px] = acc * rs;
    }
}

// ---- fp16 padded-tensor helpers ----

// store 4-px strip (both channels) + zero the x-pads when at the row edge
__device__ __forceinline__ void store_padded_h(
    _Float16* outp, int b2, int y, int x0, const v2f (&o)[4])
{
    int ob = b2 * PPLANE + y * PPITCH + x0 + PXOFF;   // multiple of 4 -> 8B aligned
    h4v h0, h1;
    h0.x = (_Float16)o[0].x; h0.y = (_Float16)o[1].x; h0.z = (_Float16)o[2].x; h0.w = (_Float16)o[3].x;
    h1.x = (_Float16)o[0].y; h1.y = (_Float16)o[1].y; h1.z = (_Float16)o[2].y; h1.w = (_Float16)o[3].y;
    *reinterpret_cast<h4v*>(outp + ob)          = h0;
    *reinterpret_cast<h4v*>(outp + ob + PPLANE) = h1;
    if (x0 == 0 || x0 == W - 4) {
        h4v z; z.x = z.y = z.z = z.w = (_Float16)0.f;
        int pb = b2 * PPLANE + y * PPITCH + (x0 == 0 ? 0 : PXOFF + W);
        *reinterpret_cast<h4v*>(outp + pb)          = z;
        *reinterpret_cast<h4v*>(outp + pb + PPLANE) = z;
    }
}

// load relu'd 3x6 neighborhood from a padded fp16 tensor (x-pads zero, y wave-uniform)
__device__ __forceinline__ void load_t_padded_h(
    unsigned s, const _Float16* __restrict__ xp, v2f (&t)[3][6])
{
    int x0 = (s & 127) * 4;
    int y  = (s >> 7) & 511;
    int b  = s >> 16;

    const _Float16* xb0 = xp + (b * 2) * PPLANE + x0 + PXOFF;
#pragma unroll
    for (int r = 0; r < 3; ++r) {
        int gy = y - 1 + r;
        bool ok = (unsigned)gy < (unsigned)H;   // wave-uniform
        int gyc = ok ? gy : y;
        const _Float16* p0 = xb0 + gyc * PPITCH;
        const _Float16* p1 = p0 + PPLANE;
        h2v a0 = *reinterpret_cast<const h2v*>(p0 - 2);
        h2v a1 = *reinterpret_cast<const h2v*>(p0);
        h2v a2 = *reinterpret_cast<const h2v*>(p0 + 2);
        h2v a3 = *reinterpret_cast<const h2v*>(p0 + 4);
        h2v c0 = *reinterpret_cast<const h2v*>(p1 - 2);
        h2v c1 = *reinterpret_cast<const h2v*>(p1);
        h2v c2 = *reinterpret_cast<const h2v*>(p1 + 2);
        h2v c3 = *reinterpret_cast<const h2v*>(p1 + 4);
        if (ok) {
            t[r][0].x = reluf((float)a0.y); t[r][0].y = reluf((float)c0.y);
            t[r][1].x = reluf((float)a1.x); t[r][1].y = reluf((float)c1.x);
            t[r][2].x = reluf((float)a1.y); t[r][2].y = reluf((float)c1.y);
            t[r][3].x = reluf((float)a2.x); t[r][3].y = reluf((float)c2.x);
            t[r][4].x = reluf((float)a2.y); t[r][4].y = reluf((float)c2.y);
            t[r][5].x = reluf((float)a3.x); t[r][5].y = reluf((float)c3.x);
        } else {
#pragma unroll
            for (int c = 0; c < 6; ++c) { t[r][c].x = 0.f; t[r][c].y = 0.f; }
        }
    }
}

// load relu'd 3x6 neighborhood from an UNPADDED f32 tensor (bounds-checked)
__device__ __forceinline__ void load_t_unpadded(
    unsigned s, const float* __restrict__ x, v2f (&t)[3][6])
{
    int x0 = (s & 127) * 4;
    int y  = (s >> 7) & 511;
    int b  = s >> 16;

    const float* xb = x + b * BSTRIDE;
    bool rowv[3] = { y > 0, true, y < H - 1 };
    int  yr[3]   = { y > 0 ? y - 1 : 0, y, y < H - 1 ? y + 1 : H - 1 };
    bool lv   = x0 > 0;
    bool rvld = x0 < W - 4;
    int  xl = lv ? x0 - 1 : 0;
    int  xr = rvld ? x0 + 4 : W - 1;

#pragma unroll
    for (int r = 0; r < 3; ++r) {
        const float* p0 = xb + yr[r] * W;
        const float* p1 = p0 + PLANE;
        float4 a0 = *reinterpret_cast<const float4*>(p0 + x0);
        float4 a1 = *reinterpret_cast<const float4*>(p1 + x0);
        float u0[6] = { p0[xl], a0.x, a0.y, a0.z, a0.w, p0[xr] };
        float u1[6] = { p1[xl], a1.x, a1.y, a1.z, a1.w, p1[xr] };
        bool rv_ = rowv[r];
#pragma unroll
        for (int c = 0; c < 6; ++c) {
            bool ok = rv_ && (c > 0 || lv) && (c < 5 || rvld);
            t[r][c].x = ok ? reluf(u0[c]) : 0.f;
            t[r][c].y = ok ? reluf(u1[c]) : 0.f;
        }
    }
}

// ---------------- kernels ----------------

// K1 (batched): t1 = attn0(relu(in1)) -> A ; t3 = attn2(relu(in2)) -> B  (fp16 padded)
__global__ __launch_bounds__(256) void attn_in_kernel(
    const float* __restrict__ xA, const float* __restrict__ xB,
    _Float16* outA, _Float16* outB,
    const float* __restrict__ wq, const float* __restrict__ bq,
    const float* __restrict__ wk, const float* __restrict__ bk,
    const float* __restrict__ wv, const float* __restrict__ bv,
    const float* __restrict__ rh, const float* __restrict__ rw,
    int piA, int piB)
{
    unsigned wid = swz8(blockIdx.x, 4096);
    bool second = wid >= 2048;
    AttnW P = load_w(wq, bq, wk, bk, wv, bv, rh, rw, second ? piB : piA);
    unsigned s = (second ? wid - 2048 : wid) * 256u + threadIdx.x;

    v2f t[3][6];
    load_t_unpadded(s, second ? xB : xA, t);
    v2f o[4];
    attn_strip(t, P, o);

    store_padded_h(second ? outB : outA, (s >> 16) * 2, (s >> 7) & 511, (s & 127) * 4, o);
}

// K23 (fused): s = attn3(t3) + in2 + (attn1(t1) + in1) -> C (fp16 padded)
__global__ __launch_bounds__(256) void attn_fused23_kernel(
    const _Float16* __restrict__ A, const _Float16* __restrict__ Bb,
    const float* __restrict__ in1, const float* __restrict__ in2,
    _Float16* __restrict__ C,
    const float* __restrict__ wq, const float* __restrict__ bq,
    const float* __restrict__ wk, const float* __restrict__ bk,
    const float* __restrict__ wv, const float* __restrict__ bv,
    const float* __restrict__ rh, const float* __restrict__ rw)
{
    unsigned s = swz8(blockIdx.x, 2048) * 256u + threadIdx.x;
    int x0 = (s & 127) * 4;
    int y  = (s >> 7) & 511;
    int b  = s >> 16;
    int base0 = b * BSTRIDE + y * W + x0;
    int base1 = base0 + PLANE;

    v2f t[3][6];
    v2f o1[4], o2[4];

    {
        AttnW P1 = load_w(wq, bq, wk, bk, wv, bv, rh, rw, 1);
        load_t_padded_h(s, A, t);
        attn_strip(t, P1, o1);
        float4 ra = *reinterpret_cast<const float4*>(in1 + base0);
        float4 rb = *reinterpret_cast<const float4*>(in1 + base1);
        o1[0].x += ra.x; o1[1].x += ra.y; o1[2].x += ra.z; o1[3].x += ra.w;
        o1[0].y += rb.x; o1[1].y += rb.y; o1[2].y += rb.z; o1[3].y += rb.w;
    }
    {
        AttnW P3 = load_w(wq, bq, wk, bk, wv, bv, rh, rw, 3);
        load_t_padded_h(s, Bb, t);
        attn_strip(t, P3, o2);
        float4 ra = *reinterpret_cast<const float4*>(in2 + base0);
        float4 rb = *reinterpret_cast<const float4*>(in2 + base1);
        o2[0].x += ra.x + o1[0].x; o2[1].x += ra.y + o1[1].x;
        o2[2].x += ra.z + o1[2].x; o2[3].x += ra.w + o1[3].x;
        o2[0].y += rb.x + o1[0].y; o2[1].y += rb.y + o1[1].y;
        o2[2].y += rb.z + o1[2].y; o2[3].y += rb.w + o1[3].y;
    }

    store_padded_h(C, b * 2, y, x0, o2);
}

// K4: t5 = attn4(relu(s)) -> B (fp16 padded); s is fp16 padded -> fast loader
__global__ __launch_bounds__(256) void attn4_kernel(
    const _Float16* __restrict__ C, _Float16* __restrict__ Bb,
    const float* __restrict__ wq, const float* __restrict__ bq,
    const float* __restrict__ wk, const float* __restrict__ bk,
    const float* __restrict__ wv, const float* __restrict__ bv,
    const float* __restrict__ rh, const float* __restrict__ rw)
{
    unsigned s = swz8(blockIdx.x, 2048) * 256u + threadIdx.x;
    AttnW P = load_w(wq, bq, wk, bk, wv, bv, rh, rw, 4);
    v2f t[3][6];
    load_t_padded_h(s, C, t);
    v2f o[4];
    attn_strip(t, P, o);
    store_padded_h(Bb, (s >> 16) * 2, (s >> 7) & 511, (s & 127) * 4, o);
}

// K5: u = attn5(relu(t5)) + s -> C in-place (own-pixel read+write only; pads untouched)
__global__ __launch_bounds__(256) void attn5_kernel(
    const _Float16* __restrict__ Bb, _Float16* __restrict__ C,
    const float* __restrict__ wq, const float* __restrict__ bq,
    const float* __restrict__ wk, const float* __restrict__ bk,
    const float* __restrict__ wv, const float* __restrict__ bv,
    const float* __restrict__ rh, const float* __restrict__ rw)
{
    unsigned s = swz8(blockIdx.x, 2048) * 256u + threadIdx.x;
    AttnW P = load_w(wq, bq, wk, bk, wv, bv, rh, rw, 5);
    v2f t[3][6];
    load_t_padded_h(s, Bb, t);
    v2f o[4];
    attn_strip(t, P, o);

    int x0 = (s & 127) * 4;
    int y  = (s >> 7) & 511;
    int b  = s >> 16;
    int ob = (b * 2) * PPLANE + y * PPITCH + x0 + PXOFF;
    h4v r0 = *reinterpret_cast<const h4v*>(C + ob);
    h4v r1 = *reinterpret_cast<const h4v*>(C + ob + PPLANE);
    o[0].x += (float)r0.x; o[1].x += (float)r0.y; o[2].x += (float)r0.z; o[3].x += (float)r0.w;
    o[0].y += (float)r1.x; o[1].y += (float)r1.y; o[2].y += (float)r1.z; o[3].y += (float)r1.w;

    h4v h0, h1;
    h0.x = (_Float16)o[0].x; h0.y = (_Float16)o[1].x; h0.z = (_Float16)o[2].x; h0.w = (_Float16)o[3].x;
    h1.x = (_Float16)o[0].y; h1.y = (_Float16)o[1].y; h1.z = (_Float16)o[2].y; h1.w = (_Float16)o[3].y;
    *reinterpret_cast<h4v*>(C + ob)          = h0;
    *reinterpret_cast<h4v*>(C + ob + PPLANE) = h1;
}

// K6: o = sigmoid(conv3x3(reflect_pad(u))) ; u is fp16 padded -> f32 out[0:2M]
__global__ __launch_bounds__(256) void conv_sig4_kernel(
    const _Float16* __restrict__ u,
    const float* __restrict__ cw, const float* __restrict__ cb,
    float* __restrict__ o)
{
    unsigned s = swz8(blockIdx.x, 2048) * 256u + threadIdx.x;
    int x0 = (s & 127) * 4;
    int y  = (s >> 7) & 511;
    int b  = s >> 16;

    float w[18];
#pragma unroll
    for (int i = 0; i < 18; ++i) w[i] = cw[i];

    int yy[3];
#pragma unroll
    for (int i = 0; i < 3; ++i) {
        int t = y + i - 1;
        if (t < 0) t = -t;
        if (t > H - 1) t = 2 * (H - 1) - t;
        yy[i] = t;
    }
    int xl = x0 - 1; if (xl < 0) xl = 1;
    int xr = x0 + 4; if (xr > W - 1) xr = 2 * (W - 1) - xr;

    float acc[4] = { cb[0], cb[0], cb[0], cb[0] };
#pragma unroll
    for (int c = 0; c < 2; ++c) {
        const _Float16* up = u + (b * 2 + c) * PPLANE + PXOFF;
#pragma unroll
        for (int i = 0; i < 3; ++i) {
            const _Float16* row = up + yy[i] * PPITCH;
            h2v m0 = *reinterpret_cast<const h2v*>(row + x0);
            h2v m1 = *reinterpret_cast<const h2v*>(row + x0 + 2);
            float t6[6] = { (float)row[xl], (float)m0.x, (float)m0.y,
                            (float)m1.x, (float)m1.y, (float)row[xr] };
#pragma unroll
            for (int j = 0; j < 3; ++j) {
                float wc = w[c * 9 + i * 3 + j];
#pragma unroll
                for (int px = 0; px < 4; ++px)
                    acc[px] = fmaf(t6[px + j], wc, acc[px]);
            }
        }
    }
    float4 ov;
    ov.x = frcp(1.f + EXP2F(-acc[0] * LOG2E));
    ov.y = frcp(1.f + EXP2F(-acc[1] * LOG2E));
    ov.z = frcp(1.f + EXP2F(-acc[2] * LOG2E));
    ov.w = frcp(1.f + EXP2F(-acc[3] * LOG2E));
    *reinterpret_cast<float4*>(o + b * PLANE + y * W + x0) = ov;
}

// K7: 2x bilinear upsample (linspace(0,511,1024) grid); o is f32
__global__ __launch_bounds__(256) void upsample4_kernel(
    const float* __restrict__ o, float* __restrict__ up)
{
    unsigned p = swz8(blockIdx.x, 8192) * 256u + threadIdx.x;
    int b  = p >> 18;
    int y  = (p >> 8) & 1023;
    int x0 = (p & 255) * 4;

    const float scale = 511.0f / 1023.0f;
    float fy = y * scale;
    int y0 = (int)fy;
    float wy = fy - y0;
    int y1 = min(y0 + 1, H - 1);

    const float* ob = o + b * PLANE;
    const float* row0 = ob + y0 * W;
    const float* row1 = ob + y1 * W;

    float4 ov;
    float* ovp = &ov.x;
#pragma unroll
    for (int j = 0; j < 4; ++j) {
        float fx = (x0 + j) * scale;
        int xi = (int)fx;
        float wx = fx - xi;
        int xi1 = min(xi + 1, W - 1);
        float v00 = row0[xi], v01 = row0[xi1];
        float v10 = row1[xi], v11 = row1[xi1];
        float top = fmaf(v01 - v00, wx, v00);
        float bot = fmaf(v11 - v10, wx, v10);
        ovp[j] = fmaf(bot - top, wy, top);
    }
    *reinterpret_cast<float4*>(up + ((long)b << 20) + y * 1024 + x0) = ov;
}

extern "C" void kernel_launch(void* const* d_in, const int* in_sizes, int n_in,
                              void* d_out, int out_size, void* d_ws, size_t ws_size,
                              hipStream_t stream) {
    const float* in1 = (const float*)d_in[0];
    const float* in2 = (const float*)d_in[1];
    const float* wq  = (const float*)d_in[2];
    const float* bq  = (const float*)d_in[3];
    const float* wk  = (const float*)d_in[4];
    const float* bk  = (const float*)d_in[5];
    const float* wv  = (const float*)d_in[6];
    const float* bv  = (const float*)d_in[7];
    const float* rh  = (const float*)d_in[8];
    const float* rw  = (const float*)d_in[9];
    const float* cw  = (const float*)d_in[10];
    const float* cb  = (const float*)d_in[11];

    float* out = (float*)d_out;
    // fp16 padded tensors (8.5MB each):
    //   A = t1            in d_out bytes [0, 8.52MB)  — dead after K23 (K6 writes o at [0,8.39MB) later)
    //   B = t3, then t5   in d_out bytes [8.52, 17.04MB) — dead after K5 (K7 writes up at [8.39,41.9MB) later)
    //   C = s, then u     in d_ws  (8.5MB of 16MB)
    _Float16* A  = (_Float16*)out;
    _Float16* Bb = (_Float16*)out + PBUF;
    _Float16* C  = (_Float16*)d_ws;
    (void)ws_size; (void)out_size; (void)n_in; (void)in_sizes;

    dim3 blk(256);

    // K1: t1 = attn0(relu(in1)) -> A ; t3 = attn2(relu(in2)) -> B
    attn_in_kernel<<<4096, blk, 0, stream>>>(in1, in2, A, Bb,
        wq, bq, wk, bk, wv, bv, rh, rw, 0, 2);
    // K23: s = attn3(relu(t3)) + in2 + (attn1(relu(t1)) + in1) -> C
    attn_fused23_kernel<<<2048, blk, 0, stream>>>(A, Bb, in1, in2, C,
        wq, bq, wk, bk, wv, bv, rh, rw);
    // K4: t5 = attn4(relu(s)) -> B
    attn4_kernel<<<2048, blk, 0, stream>>>(C, Bb,
        wq, bq, wk, bk, wv, bv, rh, rw);
    // K5: u = attn5(relu(t5)) + s -> C (in-place)
    attn5_kernel<<<2048, blk, 0, stream>>>(Bb, C,
        wq, bq, wk, bk, wv, bv, rh, rw);
    // K6: o = sigmoid(conv3x3(reflect_pad(u))) -> out[0:2M]
    conv_sig4_kernel<<<2048, blk, 0, stream>>>(C, cw, cb, out);
    // K7: up = bilinear2x(o) -> out[2M:]
    upsample4_kernel<<<8192, blk, 0, stream>>>(out, out + NPIX);
}